// Round 1
// baseline (366.801 us; speedup 1.0000x reference)
//
#include <hip/hip_runtime.h>
#include <hip/hip_bf16.h>
#include <stdint.h>

typedef __attribute__((ext_vector_type(8))) short bf16x8;
typedef __attribute__((ext_vector_type(4))) float f32x4;

#define S_LEN 2048
#define D_DIM 128
#define HQ_N  32
#define QBLK  64
#define KVBLK 64
#define KPAD  136   // 128 + 8 bf16 -> row stride 272B (16B-aligned, breaks bank conflict)
#define VPAD  72    // 64 + 8 bf16  -> row stride 144B (16B-aligned)

__device__ __forceinline__ ushort f2bf(float f) {
  union { float f; uint32_t u; } c; c.f = f;
  uint32_t u = c.u;
  u += 0x7FFFu + ((u >> 16) & 1u);   // round-nearest-even to bf16
  return (ushort)(u >> 16);
}

__global__ __launch_bounds__(256, 3) void attn_fwd(
    const float* __restrict__ Q, const float* __restrict__ K,
    const float* __restrict__ V, float* __restrict__ O) {
  const int qt   = blockIdx.x;      // q tile (64 rows)
  const int h    = blockIdx.y;      // q head
  const int hkv  = h >> 2;          // GQA: 4 q-heads per kv-head (contiguous repeat)
  const int tid  = threadIdx.x;
  const int w    = tid >> 6;        // wave 0..3
  const int lane = tid & 63;
  const int l15  = lane & 15;
  const int hgrp = lane >> 4;       // 0..3

  __shared__ ushort K_lds[KVBLK][KPAD];     // [kv][d]
  __shared__ ushort Vt_lds[D_DIM][VPAD];    // [d][kv] (transposed)
  __shared__ ushort P_lds[4][16][VPAD];     // per-wave scratch [qrow][kv]

  const float scale = 0.08838834764831845f; // 1/sqrt(128)

  // ---- Q fragments (A operand), held in registers for whole kernel ----
  // lane supplies Q[row=l15][k = ks*32 + 8*hgrp + i]  (assumed-symmetric layout)
  bf16x8 qf[4];
  {
    const int qrow = qt * QBLK + w * 16 + l15;
    const float* qp = Q + ((size_t)h * S_LEN + qrow) * D_DIM;
    for (int ks = 0; ks < 4; ++ks) {
      const float* p = qp + ks * 32 + 8 * hgrp;
      float4 a = *(const float4*)(p);
      float4 b = *(const float4*)(p + 4);
      bf16x8 f;
      f[0] = (short)f2bf(a.x * scale); f[1] = (short)f2bf(a.y * scale);
      f[2] = (short)f2bf(a.z * scale); f[3] = (short)f2bf(a.w * scale);
      f[4] = (short)f2bf(b.x * scale); f[5] = (short)f2bf(b.y * scale);
      f[6] = (short)f2bf(b.z * scale); f[7] = (short)f2bf(b.w * scale);
      qf[ks] = f;
    }
  }

  f32x4 o[8];
  for (int i = 0; i < 8; ++i) o[i] = (f32x4){0.f, 0.f, 0.f, 0.f};
  float m[4]    = {-1e30f, -1e30f, -1e30f, -1e30f};
  float lsum[4] = {0.f, 0.f, 0.f, 0.f};

  const size_t kvbase = (size_t)hkv * S_LEN * D_DIM;

  for (int kt = 0; kt <= qt; ++kt) {
    __syncthreads();   // previous tile's LDS reads done
    // ---- stage K (row-major) and V (transposed) as bf16 ----
    for (int it = 0; it < 8; ++it) {
      int idx = it * 256 + tid;        // 0..2047 float4 chunks
      int r   = idx >> 5;              // kv row 0..63
      int c   = (idx & 31) * 4;        // d col
      const size_t g = kvbase + ((size_t)(kt * KVBLK + r)) * D_DIM + c;
      float4 kv4 = *(const float4*)(K + g);
      ushort4 kb;
      kb.x = f2bf(kv4.x); kb.y = f2bf(kv4.y);
      kb.z = f2bf(kv4.z); kb.w = f2bf(kv4.w);
      *(ushort4*)&K_lds[r][c] = kb;
      float4 vv4 = *(const float4*)(V + g);
      Vt_lds[c + 0][r] = f2bf(vv4.x);
      Vt_lds[c + 1][r] = f2bf(vv4.y);
      Vt_lds[c + 2][r] = f2bf(vv4.z);
      Vt_lds[c + 3][r] = f2bf(vv4.w);
    }
    __syncthreads();   // tile staged

    // ---- S = Q K^T : 4 n-frags of 16 kv cols, accumulate over 4 k-slices ----
    f32x4 s[4];
    for (int n = 0; n < 4; ++n) s[n] = (f32x4){0.f, 0.f, 0.f, 0.f};
    for (int n = 0; n < 4; ++n) {
      for (int ks = 0; ks < 4; ++ks) {
        bf16x8 kf = *(const bf16x8*)&K_lds[n * 16 + l15][ks * 32 + 8 * hgrp];
        s[n] = __builtin_amdgcn_mfma_f32_16x16x32_bf16(qf[ks], kf, s[n], 0, 0, 0);
      }
    }

    // ---- causal mask (diagonal tile only; kt==qt so compare tile-relative) ----
    if (kt == qt) {
      for (int n = 0; n < 4; ++n)
        for (int r = 0; r < 4; ++r)
          if (n * 16 + l15 > w * 16 + 4 * hgrp + r) s[n][r] = -1e30f;
    }

    // ---- online softmax (row stats replicated across each 16-lane group) ----
    float mnew[4], alpha[4];
    for (int r = 0; r < 4; ++r) {
      float mx = fmaxf(fmaxf(s[0][r], s[1][r]), fmaxf(s[2][r], s[3][r]));
      mx = fmaxf(mx, __shfl_xor(mx, 1));
      mx = fmaxf(mx, __shfl_xor(mx, 2));
      mx = fmaxf(mx, __shfl_xor(mx, 4));
      mx = fmaxf(mx, __shfl_xor(mx, 8));
      mnew[r]  = fmaxf(m[r], mx);
      alpha[r] = __expf(m[r] - mnew[r]);
      m[r]     = mnew[r];
    }
    float rs[4] = {0.f, 0.f, 0.f, 0.f};
    for (int n = 0; n < 4; ++n)
      for (int r = 0; r < 4; ++r) {
        float p = __expf(s[n][r] - mnew[r]);
        s[n][r] = p;
        rs[r] += p;
      }
    for (int r = 0; r < 4; ++r) {
      float t = rs[r];
      t += __shfl_xor(t, 1); t += __shfl_xor(t, 2);
      t += __shfl_xor(t, 4); t += __shfl_xor(t, 8);
      lsum[r] = lsum[r] * alpha[r] + t;
    }

    // ---- P -> LDS (bf16), per-wave private scratch ----
    for (int n = 0; n < 4; ++n)
      for (int r = 0; r < 4; ++r)
        P_lds[w][4 * hgrp + r][n * 16 + l15] = f2bf(s[n][r]);

    // ---- rescale O by alpha ----
    for (int dt = 0; dt < 8; ++dt)
      for (int r = 0; r < 4; ++r) o[dt][r] *= alpha[r];

    // ---- O += P V : A=P (row=l15), B=V^T (col=l15=d), k=kv ----
    bf16x8 pf[2];
    for (int kk = 0; kk < 2; ++kk)
      pf[kk] = *(const bf16x8*)&P_lds[w][l15][kk * 32 + 8 * hgrp];
    for (int dt = 0; dt < 8; ++dt)
      for (int kk = 0; kk < 2; ++kk) {
        bf16x8 vf = *(const bf16x8*)&Vt_lds[dt * 16 + l15][kk * 32 + 8 * hgrp];
        o[dt] = __builtin_amdgcn_mfma_f32_16x16x32_bf16(pf[kk], vf, o[dt], 0, 0, 0);
      }
  }

  // ---- epilogue: divide by softmax denom, write f32 ----
  const int qrow = qt * QBLK + w * 16 + 4 * hgrp;
  for (int r = 0; r < 4; ++r) {
    float inv = 1.0f / lsum[r];
    float* op = O + ((size_t)h * S_LEN + qrow + r) * D_DIM + l15;
    for (int dt = 0; dt < 8; ++dt)
      op[dt * 16] = o[dt][r] * inv;
  }
}

extern "C" void kernel_launch(void* const* d_in, const int* in_sizes, int n_in,
                              void* d_out, int out_size, void* d_ws, size_t ws_size,
                              hipStream_t stream) {
  const float* Q = (const float*)d_in[0];
  const float* K = (const float*)d_in[1];
  const float* V = (const float*)d_in[2];
  float* O = (float*)d_out;
  dim3 grid(S_LEN / QBLK, HQ_N);
  attn_fwd<<<grid, dim3(256), 0, stream>>>(Q, K, V, O);
}

// Round 2
// 112.305 us; speedup vs baseline: 3.2661x; 3.2661x over previous
//
#include <hip/hip_runtime.h>
#include <hip/hip_bf16.h>
#include <stdint.h>

typedef __attribute__((ext_vector_type(8))) short bf16x8;
typedef __attribute__((ext_vector_type(4))) float f32x4;

#define S_LEN 2048
#define D_DIM 128
#define HQ_N  32
#define NKT   32          // 32 kv tiles of 64 rows
#define TILE_USH 8192     // 64*128 bf16 per tile = 16KB

__device__ __forceinline__ ushort f2bf(float f) {
  union { float f; uint32_t u; } c; c.f = f;
  uint32_t u = c.u;
  u += 0x7FFFu + ((u >> 16) & 1u);   // round-nearest-even
  return (ushort)(u >> 16);
}

__device__ __forceinline__ void gload16(const void* g, void* l) {
  __builtin_amdgcn_global_load_lds(
      (const __attribute__((address_space(1))) uint32_t*)g,
      (__attribute__((address_space(3))) uint32_t*)l, 16, 0, 0);
}

// ---- prepass: K fp32 row-major -> bf16 tiles, chunk-swizzled ----
// tile = hkv*32+kt (16KB). Element (r,d): byte = r*256 + ((d>>3)^(r&15))*16 + (d&7)*2
__global__ __launch_bounds__(256) void prep_k(const float* __restrict__ K,
                                              ushort* __restrict__ KT) {
  int tid  = blockIdx.x * 256 + threadIdx.x;   // 262144
  int tile = tid >> 10;
  int off  = tid & 1023;       // physical 16B chunk in tile
  int r    = off >> 4;
  int gp   = off & 15;
  int g    = gp ^ (r & 15);
  const float* src = K + ((size_t)(tile * 64 + r)) * D_DIM + (g << 3);
  float4 x = *(const float4*)src;
  float4 y = *(const float4*)(src + 4);
  union { ushort u[8]; bf16x8 v; } o;
  o.u[0] = f2bf(x.x); o.u[1] = f2bf(x.y); o.u[2] = f2bf(x.z); o.u[3] = f2bf(x.w);
  o.u[4] = f2bf(y.x); o.u[5] = f2bf(y.y); o.u[6] = f2bf(y.z); o.u[7] = f2bf(y.w);
  *(bf16x8*)(KT + (size_t)tid * 8) = o.v;
}

// ---- prepass: V fp32 -> bf16 TRANSPOSED tiles [d=128][kv=64], chunk-swizzled ----
// Element (d,kv): byte = d*128 + ((kv>>3)^(d&7))*16 + (kv&7)*2
__global__ __launch_bounds__(256) void prep_v(const float* __restrict__ V,
                                              ushort* __restrict__ VT) {
  int tid  = blockIdx.x * 256 + threadIdx.x;   // 262144
  int tile = tid >> 10;        // hkv*32+kt
  int off  = tid & 1023;       // = d*8 + gp
  int d    = off >> 3;
  int gp   = off & 7;
  int g    = gp ^ (d & 7);
  int kv0  = (tile & 31) * 64 + (g << 3);
  const float* src = V + ((size_t)(tile >> 5) * S_LEN + kv0) * D_DIM + d;
  union { ushort u[8]; bf16x8 v; } o;
  #pragma unroll
  for (int j = 0; j < 8; ++j) o.u[j] = f2bf(src[(size_t)j * D_DIM]);
  *(bf16x8*)(VT + (size_t)tid * 8) = o.v;
}

// ---- process one staged 64x64 kv tile against one 64-row q subtile ----
__device__ __forceinline__ void process_tile(
    const ushort* Kl, const ushort* Vl, ushort (*Pw)[72],
    const bf16x8* qf, f32x4* o, float* m, float* lsum,
    bool diag, int w, int l15, int hgrp) {
  f32x4 s[4];
  #pragma unroll
  for (int n = 0; n < 4; ++n) s[n] = (f32x4){0.f, 0.f, 0.f, 0.f};
  #pragma unroll
  for (int n = 0; n < 4; ++n) {
    const char* rowp = (const char*)Kl + (n * 16 + l15) * 256;
    #pragma unroll
    for (int ks = 0; ks < 4; ++ks) {
      bf16x8 kf = *(const bf16x8*)(rowp + ((((ks << 2) + hgrp) ^ l15) << 4));
      s[n] = __builtin_amdgcn_mfma_f32_16x16x32_bf16(qf[ks], kf, s[n], 0, 0, 0);
    }
  }
  if (diag) {
    #pragma unroll
    for (int n = 0; n < 4; ++n)
      #pragma unroll
      for (int r = 0; r < 4; ++r)
        if (n * 16 + l15 > w * 16 + 4 * hgrp + r) s[n][r] = -1e30f;
  }
  float mnew[4], alpha[4];
  #pragma unroll
  for (int r = 0; r < 4; ++r) {
    float mx = fmaxf(fmaxf(s[0][r], s[1][r]), fmaxf(s[2][r], s[3][r]));
    mx = fmaxf(mx, __shfl_xor(mx, 1));
    mx = fmaxf(mx, __shfl_xor(mx, 2));
    mx = fmaxf(mx, __shfl_xor(mx, 4));
    mx = fmaxf(mx, __shfl_xor(mx, 8));
    mnew[r]  = fmaxf(m[r], mx);
    alpha[r] = __expf(m[r] - mnew[r]);
    m[r]     = mnew[r];
  }
  float rs[4] = {0.f, 0.f, 0.f, 0.f};
  #pragma unroll
  for (int n = 0; n < 4; ++n)
    #pragma unroll
    for (int r = 0; r < 4; ++r) {
      float p = __expf(s[n][r] - mnew[r]);
      s[n][r] = p;
      rs[r] += p;
    }
  #pragma unroll
  for (int r = 0; r < 4; ++r) {
    float t = rs[r];
    t += __shfl_xor(t, 1); t += __shfl_xor(t, 2);
    t += __shfl_xor(t, 4); t += __shfl_xor(t, 8);
    lsum[r] = lsum[r] * alpha[r] + t;
  }
  #pragma unroll
  for (int n = 0; n < 4; ++n)
    #pragma unroll
    for (int r = 0; r < 4; ++r)
      Pw[4 * hgrp + r][n * 16 + l15] = f2bf(s[n][r]);
  #pragma unroll
  for (int dt = 0; dt < 8; ++dt)
    #pragma unroll
    for (int r = 0; r < 4; ++r) o[dt][r] *= alpha[r];
  bf16x8 pf0 = *(const bf16x8*)&Pw[l15][8 * hgrp];
  bf16x8 pf1 = *(const bf16x8*)&Pw[l15][32 + 8 * hgrp];
  #pragma unroll
  for (int dt = 0; dt < 8; ++dt) {
    const char* vrow = (const char*)Vl + (dt * 16 + l15) * 128;
    bf16x8 vf0 = *(const bf16x8*)(vrow + ((hgrp ^ (l15 & 7)) << 4));
    bf16x8 vf1 = *(const bf16x8*)(vrow + (((4 + hgrp) ^ (l15 & 7)) << 4));
    o[dt] = __builtin_amdgcn_mfma_f32_16x16x32_bf16(pf0, vf0, o[dt], 0, 0, 0);
    o[dt] = __builtin_amdgcn_mfma_f32_16x16x32_bf16(pf1, vf1, o[dt], 0, 0, 0);
  }
}

__global__ __launch_bounds__(256, 2) void attn_fwd(
    const float* __restrict__ Q, const ushort* __restrict__ KT,
    const ushort* __restrict__ VT, float* __restrict__ O) {
  const int a    = blockIdx.x;        // 0..15; paired with b=31-a (equal work: 33 tiles)
  const int b    = 31 - a;
  const int h    = blockIdx.y;
  const int hkv  = h >> 2;
  const int tid  = threadIdx.x;
  const int w    = tid >> 6;
  const int lane = tid & 63;
  const int l15  = lane & 15;
  const int hgrp = lane >> 4;

  __shared__ ushort K_lds[TILE_USH];
  __shared__ ushort V_lds[TILE_USH];
  __shared__ ushort P_lds[4][16][72];

  const float scale = 0.08838834764831845f;

  bf16x8 qfA[4], qfB[4];
  {
    const float* qa = Q + ((size_t)h * S_LEN + a * 64 + w * 16 + l15) * D_DIM;
    const float* qb = Q + ((size_t)h * S_LEN + b * 64 + w * 16 + l15) * D_DIM;
    #pragma unroll
    for (int ks = 0; ks < 4; ++ks) {
      const float* pa = qa + ks * 32 + 8 * hgrp;
      const float* pb = qb + ks * 32 + 8 * hgrp;
      bf16x8 fa, fb;
      #pragma unroll
      for (int j = 0; j < 8; ++j) {
        fa[j] = (short)f2bf(pa[j] * scale);
        fb[j] = (short)f2bf(pb[j] * scale);
      }
      qfA[ks] = fa; qfB[ks] = fb;
    }
  }

  f32x4 oA[8], oB[8];
  #pragma unroll
  for (int i = 0; i < 8; ++i) {
    oA[i] = (f32x4){0.f, 0.f, 0.f, 0.f};
    oB[i] = (f32x4){0.f, 0.f, 0.f, 0.f};
  }
  float mA[4], lA[4], mB[4], lB[4];
  #pragma unroll
  for (int r = 0; r < 4; ++r) { mA[r] = mB[r] = -1e30f; lA[r] = lB[r] = 0.f; }

  const ushort* ktiles = KT + ((size_t)hkv * NKT) * TILE_USH;
  const ushort* vtiles = VT + ((size_t)hkv * NKT) * TILE_USH;

  for (int kt = 0; kt <= b; ++kt) {
    __syncthreads();   // previous tile's LDS reads complete
    const char* gk = (const char*)(ktiles + (size_t)kt * TILE_USH);
    const char* gv = (const char*)(vtiles + (size_t)kt * TILE_USH);
    #pragma unroll
    for (int i = 0; i < 4; ++i) {
      int off = w * 4096 + i * 1024;
      gload16(gk + off + lane * 16, (char*)K_lds + off);
      gload16(gv + off + lane * 16, (char*)V_lds + off);
    }
    __syncthreads();   // staged (compiler drains vmcnt before barrier)

    process_tile(K_lds, V_lds, P_lds[w], qfB, oB, mB, lB, kt == b, w, l15, hgrp);
    if (kt <= a)
      process_tile(K_lds, V_lds, P_lds[w], qfA, oA, mA, lA, kt == a, w, l15, hgrp);
  }

  // epilogue
  #pragma unroll
  for (int r = 0; r < 4; ++r) {
    float invB = 1.0f / lB[r];
    float* opB = O + ((size_t)h * S_LEN + b * 64 + w * 16 + 4 * hgrp + r) * D_DIM + l15;
    #pragma unroll
    for (int dt = 0; dt < 8; ++dt) opB[dt * 16] = oB[dt][r] * invB;
    float invA = 1.0f / lA[r];
    float* opA = O + ((size_t)h * S_LEN + a * 64 + w * 16 + 4 * hgrp + r) * D_DIM + l15;
    #pragma unroll
    for (int dt = 0; dt < 8; ++dt) opA[dt * 16] = oA[dt][r] * invA;
  }
}

extern "C" void kernel_launch(void* const* d_in, const int* in_sizes, int n_in,
                              void* d_out, int out_size, void* d_ws, size_t ws_size,
                              hipStream_t stream) {
  const float* Q = (const float*)d_in[0];
  const float* K = (const float*)d_in[1];
  const float* V = (const float*)d_in[2];
  float* O = (float*)d_out;
  ushort* wsK = (ushort*)d_ws;
  ushort* wsV = wsK + (size_t)8 * NKT * TILE_USH;   // +4MB
  prep_k<<<1024, 256, 0, stream>>>(K, wsK);
  prep_v<<<1024, 256, 0, stream>>>(V, wsV);
  attn_fwd<<<dim3(16, HQ_N), 256, 0, stream>>>(Q, wsK, wsV, O);
}

// Round 3
// 109.892 us; speedup vs baseline: 3.3378x; 1.0220x over previous
//
#include <hip/hip_runtime.h>
#include <hip/hip_bf16.h>
#include <stdint.h>
#include <math.h>

typedef __attribute__((ext_vector_type(8))) short bf16x8;
typedef __attribute__((ext_vector_type(4))) float f32x4;

#define S_LEN 2048
#define D_DIM 128
#define HQ_N  32
#define NKT   32          // 32 kv tiles of 64 rows
#define TILE_USH 8192     // 64*128 bf16 per tile = 16KB

__device__ __forceinline__ ushort f2bf(float f) {
  union { float f; uint32_t u; } c; c.f = f;
  uint32_t u = c.u;
  u += 0x7FFFu + ((u >> 16) & 1u);   // round-nearest-even
  return (ushort)(u >> 16);
}

__device__ __forceinline__ void gload16(const void* g, void* l) {
  __builtin_amdgcn_global_load_lds(
      (const __attribute__((address_space(1))) uint32_t*)g,
      (__attribute__((address_space(3))) uint32_t*)l, 16, 0, 0);
}

// ---- prepass: K fp32 row-major -> bf16 tiles, chunk-swizzled ----
// tile = hkv*32+kt (16KB). Element (r,d): byte = r*256 + ((d>>3)^(r&15))*16 + (d&7)*2
__global__ __launch_bounds__(256) void prep_k(const float* __restrict__ K,
                                              ushort* __restrict__ KT) {
  int tid  = blockIdx.x * 256 + threadIdx.x;   // 262144
  int tile = tid >> 10;
  int off  = tid & 1023;       // physical 16B chunk in tile
  int r    = off >> 4;
  int gp   = off & 15;
  int g    = gp ^ (r & 15);
  const float* src = K + ((size_t)(tile * 64 + r)) * D_DIM + (g << 3);
  float4 x = *(const float4*)src;
  float4 y = *(const float4*)(src + 4);
  union { ushort u[8]; bf16x8 v; } o;
  o.u[0] = f2bf(x.x); o.u[1] = f2bf(x.y); o.u[2] = f2bf(x.z); o.u[3] = f2bf(x.w);
  o.u[4] = f2bf(y.x); o.u[5] = f2bf(y.y); o.u[6] = f2bf(y.z); o.u[7] = f2bf(y.w);
  *(bf16x8*)(KT + (size_t)tid * 8) = o.v;
}

// ---- prepass: V fp32 -> bf16 TRANSPOSED tiles [d=128][kv=64], chunk-swizzled ----
// Element (d,kv): byte = d*128 + ((kv>>3)^(d&7))*16 + (kv&7)*2
__global__ __launch_bounds__(256) void prep_v(const float* __restrict__ V,
                                              ushort* __restrict__ VT) {
  int tid  = blockIdx.x * 256 + threadIdx.x;   // 262144
  int tile = tid >> 10;        // hkv*32+kt
  int off  = tid & 1023;       // = d*8 + gp
  int d    = off >> 3;
  int gp   = off & 7;
  int g    = gp ^ (d & 7);
  int kv0  = (tile & 31) * 64 + (g << 3);
  const float* src = V + ((size_t)(tile >> 5) * S_LEN + kv0) * D_DIM + d;
  union { ushort u[8]; bf16x8 v; } o;
  #pragma unroll
  for (int j = 0; j < 8; ++j) o.u[j] = f2bf(src[(size_t)j * D_DIM]);
  *(bf16x8*)(VT + (size_t)tid * 8) = o.v;
}

// ---- process one staged 64x64 kv tile against one 64-row q subtile ----
// NOTE: scores are in log2 domain (Q pre-scaled by 1/sqrt(D) * log2(e)); exp2f used.
__device__ __forceinline__ void process_tile(
    const ushort* Kl, const ushort* Vl, ushort (*Pw)[72],
    const bf16x8* qf, f32x4* o, float* m, float* lsum,
    bool diag, int w, int l15, int hgrp) {
  f32x4 s[4];
  #pragma unroll
  for (int n = 0; n < 4; ++n) s[n] = (f32x4){0.f, 0.f, 0.f, 0.f};
  __builtin_amdgcn_s_setprio(1);
  #pragma unroll
  for (int n = 0; n < 4; ++n) {
    const char* rowp = (const char*)Kl + (n * 16 + l15) * 256;
    #pragma unroll
    for (int ks = 0; ks < 4; ++ks) {
      bf16x8 kf = *(const bf16x8*)(rowp + ((((ks << 2) + hgrp) ^ l15) << 4));
      s[n] = __builtin_amdgcn_mfma_f32_16x16x32_bf16(qf[ks], kf, s[n], 0, 0, 0);
    }
  }
  __builtin_amdgcn_s_setprio(0);
  if (diag) {
    #pragma unroll
    for (int n = 0; n < 4; ++n)
      #pragma unroll
      for (int r = 0; r < 4; ++r)
        if (n * 16 + l15 > w * 16 + 4 * hgrp + r) s[n][r] = -1e30f;
  }
  float mnew[4], alpha[4];
  #pragma unroll
  for (int r = 0; r < 4; ++r) {
    float mx = fmaxf(fmaxf(s[0][r], s[1][r]), fmaxf(s[2][r], s[3][r]));
    mx = fmaxf(mx, __shfl_xor(mx, 1));
    mx = fmaxf(mx, __shfl_xor(mx, 2));
    mx = fmaxf(mx, __shfl_xor(mx, 4));
    mx = fmaxf(mx, __shfl_xor(mx, 8));
    mnew[r]  = fmaxf(m[r], mx);
    alpha[r] = exp2f(m[r] - mnew[r]);
    m[r]     = mnew[r];
  }
  float rs[4] = {0.f, 0.f, 0.f, 0.f};
  #pragma unroll
  for (int n = 0; n < 4; ++n)
    #pragma unroll
    for (int r = 0; r < 4; ++r) {
      float p = exp2f(s[n][r] - mnew[r]);
      s[n][r] = p;
      rs[r] += p;
    }
  #pragma unroll
  for (int r = 0; r < 4; ++r) {
    float t = rs[r];
    t += __shfl_xor(t, 1); t += __shfl_xor(t, 2);
    t += __shfl_xor(t, 4); t += __shfl_xor(t, 8);
    lsum[r] = lsum[r] * alpha[r] + t;
  }
  #pragma unroll
  for (int n = 0; n < 4; ++n)
    #pragma unroll
    for (int r = 0; r < 4; ++r)
      Pw[4 * hgrp + r][n * 16 + l15] = f2bf(s[n][r]);
  #pragma unroll
  for (int dt = 0; dt < 8; ++dt)
    #pragma unroll
    for (int r = 0; r < 4; ++r) o[dt][r] *= alpha[r];
  bf16x8 pf0 = *(const bf16x8*)&Pw[l15][8 * hgrp];
  bf16x8 pf1 = *(const bf16x8*)&Pw[l15][32 + 8 * hgrp];
  __builtin_amdgcn_s_setprio(1);
  #pragma unroll
  for (int dt = 0; dt < 8; ++dt) {
    const char* vrow = (const char*)Vl + (dt * 16 + l15) * 128;
    bf16x8 vf0 = *(const bf16x8*)(vrow + ((hgrp ^ (l15 & 7)) << 4));
    bf16x8 vf1 = *(const bf16x8*)(vrow + (((4 + hgrp) ^ (l15 & 7)) << 4));
    o[dt] = __builtin_amdgcn_mfma_f32_16x16x32_bf16(pf0, vf0, o[dt], 0, 0, 0);
    o[dt] = __builtin_amdgcn_mfma_f32_16x16x32_bf16(pf1, vf1, o[dt], 0, 0, 0);
  }
  __builtin_amdgcn_s_setprio(0);
}

__global__ __launch_bounds__(256, 2) void attn_fwd(
    const float* __restrict__ Q, const ushort* __restrict__ KT,
    const ushort* __restrict__ VT, float* __restrict__ O) {
  const int a    = blockIdx.x;        // 0..15; paired with b=31-a (equal work: 33 tiles)
  const int b    = 31 - a;
  const int h    = blockIdx.y;
  const int hkv  = h >> 2;
  const int tid  = threadIdx.x;
  const int w    = tid >> 6;
  const int lane = tid & 63;
  const int l15  = lane & 15;
  const int hgrp = lane >> 4;

  __shared__ ushort K_lds[2][TILE_USH];
  __shared__ ushort V_lds[2][TILE_USH];
  __shared__ ushort P_lds[4][16][72];

  // 1/sqrt(128) * log2(e): scores computed directly in log2 domain
  const float scale = 0.08838834764831845f * 1.4426950408889634f;

  bf16x8 qfA[4], qfB[4];
  {
    const float* qa = Q + ((size_t)h * S_LEN + a * 64 + w * 16 + l15) * D_DIM;
    const float* qb = Q + ((size_t)h * S_LEN + b * 64 + w * 16 + l15) * D_DIM;
    #pragma unroll
    for (int ks = 0; ks < 4; ++ks) {
      const float* pa = qa + ks * 32 + 8 * hgrp;
      const float* pb = qb + ks * 32 + 8 * hgrp;
      bf16x8 fa, fb;
      #pragma unroll
      for (int j = 0; j < 8; ++j) {
        fa[j] = (short)f2bf(pa[j] * scale);
        fb[j] = (short)f2bf(pb[j] * scale);
      }
      qfA[ks] = fa; qfB[ks] = fb;
    }
  }

  f32x4 oA[8], oB[8];
  #pragma unroll
  for (int i = 0; i < 8; ++i) {
    oA[i] = (f32x4){0.f, 0.f, 0.f, 0.f};
    oB[i] = (f32x4){0.f, 0.f, 0.f, 0.f};
  }
  float mA[4], lA[4], mB[4], lB[4];
  #pragma unroll
  for (int r = 0; r < 4; ++r) { mA[r] = mB[r] = -1e30f; lA[r] = lB[r] = 0.f; }

  const char* ktiles = (const char*)(KT + ((size_t)hkv * NKT) * TILE_USH);
  const char* vtiles = (const char*)(VT + ((size_t)hkv * NKT) * TILE_USH);

  // ---- prologue: stage tile 0 into buffer 0 ----
  {
    #pragma unroll
    for (int i = 0; i < 4; ++i) {
      int off = w * 4096 + i * 1024 + lane * 16;
      gload16(ktiles + off, (char*)K_lds[0] + off);
      gload16(vtiles + off, (char*)V_lds[0] + off);
    }
  }
  __syncthreads();

  for (int kt = 0; kt <= b; ++kt) {
    const int cur = kt & 1;
    // ---- issue next tile's staging FIRST; latency hides under compute ----
    if (kt < b) {
      const char* gk = ktiles + (size_t)(kt + 1) * (TILE_USH * 2);
      const char* gv = vtiles + (size_t)(kt + 1) * (TILE_USH * 2);
      #pragma unroll
      for (int i = 0; i < 4; ++i) {
        int off = w * 4096 + i * 1024 + lane * 16;
        gload16(gk + off, (char*)K_lds[cur ^ 1] + off);
        gload16(gv + off, (char*)V_lds[cur ^ 1] + off);
      }
    }

    process_tile(K_lds[cur], V_lds[cur], P_lds[w], qfB, oB, mB, lB, kt == b, w, l15, hgrp);
    if (kt <= a)
      process_tile(K_lds[cur], V_lds[cur], P_lds[w], qfA, oA, mA, lA, kt == a, w, l15, hgrp);

    __syncthreads();   // drains vmcnt (next tile landed) + joins compute of cur
  }

  // epilogue
  #pragma unroll
  for (int r = 0; r < 4; ++r) {
    float invB = 1.0f / lB[r];
    float* opB = O + ((size_t)h * S_LEN + b * 64 + w * 16 + 4 * hgrp + r) * D_DIM + l15;
    #pragma unroll
    for (int dt = 0; dt < 8; ++dt) opB[dt * 16] = oB[dt][r] * invB;
    float invA = 1.0f / lA[r];
    float* opA = O + ((size_t)h * S_LEN + a * 64 + w * 16 + 4 * hgrp + r) * D_DIM + l15;
    #pragma unroll
    for (int dt = 0; dt < 8; ++dt) opA[dt * 16] = oA[dt][r] * invA;
  }
}

extern "C" void kernel_launch(void* const* d_in, const int* in_sizes, int n_in,
                              void* d_out, int out_size, void* d_ws, size_t ws_size,
                              hipStream_t stream) {
  const float* Q = (const float*)d_in[0];
  const float* K = (const float*)d_in[1];
  const float* V = (const float*)d_in[2];
  float* O = (float*)d_out;
  ushort* wsK = (ushort*)d_ws;
  ushort* wsV = wsK + (size_t)8 * NKT * TILE_USH;   // +4MB
  prep_k<<<1024, 256, 0, stream>>>(K, wsK);
  prep_v<<<1024, 256, 0, stream>>>(V, wsV);
  attn_fwd<<<dim3(16, HQ_N), 256, 0, stream>>>(Q, wsK, wsV, O);
}

// Round 4
// 94.531 us; speedup vs baseline: 3.8802x; 1.1625x over previous
//
#include <hip/hip_runtime.h>
#include <hip/hip_bf16.h>
#include <stdint.h>

typedef __attribute__((ext_vector_type(8))) short bf16x8;
typedef __attribute__((ext_vector_type(4))) float f32x4;
typedef __attribute__((ext_vector_type(16))) float f32x16;

#define S_LEN 2048
#define D_DIM 128
#define HQ_N  32
#define NKT   32          // 32 kv tiles of 64 rows per kv-head
#define TILE_USH 8192     // 64*128 bf16 per tile
#define TILE_B   16384    // bytes per tile

__device__ __forceinline__ ushort f2bf(float f) {
  union { float f; uint32_t u; } c; c.f = f;
  uint32_t u = c.u;
  u += 0x7FFFu + ((u >> 16) & 1u);   // round-nearest-even
  return (ushort)(u >> 16);
}

__device__ __forceinline__ uint32_t cvtpk(float lo, float hi) {
  uint32_t r;
  asm("v_cvt_pk_bf16_f32 %0, %1, %2" : "=v"(r) : "v"(lo), "v"(hi));
  return r;
}

__device__ __forceinline__ void gload16(const void* g, void* l) {
  __builtin_amdgcn_global_load_lds(
      (const __attribute__((address_space(1))) uint32_t*)g,
      (__attribute__((address_space(3))) uint32_t*)l, 16, 0, 0);
}

// ---- prepass: K fp32 row-major -> bf16 tiles, chunk-swizzled ----
// tile = hkv*32+kt. Element (r,d): byte = r*256 + ((d>>3)^(r&15))*16 + (d&7)*2
__global__ __launch_bounds__(256) void prep_k(const float* __restrict__ K,
                                              ushort* __restrict__ KT) {
  int tid  = blockIdx.x * 256 + threadIdx.x;   // 262144
  int tile = tid >> 10;
  int off  = tid & 1023;       // physical 16B chunk in tile
  int r    = off >> 4;
  int gp   = off & 15;
  int g    = gp ^ (r & 15);
  const float* src = K + ((size_t)(tile * 64 + r)) * D_DIM + (g << 3);
  float4 x = *(const float4*)src;
  float4 y = *(const float4*)(src + 4);
  union { ushort u[8]; bf16x8 v; } o;
  o.u[0] = f2bf(x.x); o.u[1] = f2bf(x.y); o.u[2] = f2bf(x.z); o.u[3] = f2bf(x.w);
  o.u[4] = f2bf(y.x); o.u[5] = f2bf(y.y); o.u[6] = f2bf(y.z); o.u[7] = f2bf(y.w);
  *(bf16x8*)(KT + (size_t)tid * 8) = o.v;
}

// ---- prepass: V fp32 -> bf16 TRANSPOSED tiles [d=128][kv=64], chunk-swizzled ----
// Element (d,kv): byte = d*128 + ((kv>>3)^(d&7))*16 + (kv&7)*2
__global__ __launch_bounds__(256) void prep_v(const float* __restrict__ V,
                                              ushort* __restrict__ VT) {
  int tid  = blockIdx.x * 256 + threadIdx.x;   // 262144
  int tile = tid >> 10;        // hkv*32+kt
  int off  = tid & 1023;       // = d*8 + gp
  int d    = off >> 3;
  int gp   = off & 7;
  int g    = gp ^ (d & 7);
  int kv0  = (tile & 31) * 64 + (g << 3);
  const float* src = V + ((size_t)(tile >> 5) * S_LEN + kv0) * D_DIM + d;
  union { ushort u[8]; bf16x8 v; } o;
  #pragma unroll
  for (int j = 0; j < 8; ++j) o.u[j] = f2bf(src[(size_t)j * D_DIM]);
  *(bf16x8*)(VT + (size_t)tid * 8) = o.v;
}

// ---- flash attention, swapped-operand 32x32x16, in-register softmax ----
__global__ __launch_bounds__(256, 2) void attn_fwd(
    const float* __restrict__ Q, const ushort* __restrict__ KT,
    const ushort* __restrict__ VT, float* __restrict__ O) {
  const int n    = blockIdx.x;           // 512 blocks
  const int h    = n & 31;
  const int m5   = n >> 5;               // 0..15
  const int qt   = (m5 < 8) ? m5 : 23 - m5;   // n,n+256 -> qt,15-qt (balanced)
  const int hkv  = h >> 2;
  const int tid  = threadIdx.x;
  const int w    = tid >> 6;
  const int lane = tid & 63;
  const int l31  = lane & 31;
  const int hi   = lane >> 5;
  const int qw   = qt * 128 + w * 32;    // wave's first q row
  const int qrow = qw + l31;             // this lane's q row

  __shared__ ushort K_lds[2][TILE_USH];
  __shared__ ushort V_lds[2][TILE_USH];

  const char* ktiles = (const char*)KT + (size_t)hkv * NKT * TILE_B;
  const char* vtiles = (const char*)VT + (size_t)hkv * NKT * TILE_B;
  const int nsteps = 2 * qt + 2;

  // prologue: stage tile 0 (issue before Q-load so latency overlaps)
  #pragma unroll
  for (int i = 0; i < 4; ++i) {
    int off = w * 4096 + i * 1024 + lane * 16;
    gload16(ktiles + off, (char*)K_lds[0] + off);
    gload16(vtiles + off, (char*)V_lds[0] + off);
  }

  // Q fragments (B operand): qf[s] holds Q[qrow][16s+8hi .. +7], log2-domain scale
  const float scale = 0.08838834764831845f * 1.4426950408889634f;
  bf16x8 qf[8];
  {
    const float* qp = Q + ((size_t)h * S_LEN + qrow) * D_DIM;
    #pragma unroll
    for (int s = 0; s < 8; ++s) {
      const float* p = qp + 16 * s + 8 * hi;
      float4 x = *(const float4*)p;
      float4 y = *(const float4*)(p + 4);
      bf16x8 f;
      f[0] = (short)f2bf(x.x * scale); f[1] = (short)f2bf(x.y * scale);
      f[2] = (short)f2bf(x.z * scale); f[3] = (short)f2bf(x.w * scale);
      f[4] = (short)f2bf(y.x * scale); f[5] = (short)f2bf(y.y * scale);
      f[6] = (short)f2bf(y.z * scale); f[7] = (short)f2bf(y.w * scale);
      qf[s] = f;
    }
  }

  f32x16 o[4] = {};        // O^T frags: lane: q=l31, d = 32*dt + (r&3)+8*(r>>2)+4*hi
  float mrow = -1e30f, lsum = 0.f;

  __syncthreads();

  for (int kt = 0; kt < nsteps; ++kt) {
    const int cur = kt & 1;
    if (kt + 1 < nsteps) {
      const char* gk = ktiles + (size_t)(kt + 1) * TILE_B;
      const char* gv = vtiles + (size_t)(kt + 1) * TILE_B;
      #pragma unroll
      for (int i = 0; i < 4; ++i) {
        int off = w * 4096 + i * 1024 + lane * 16;
        gload16(gk + off, (char*)K_lds[cur ^ 1] + off);
        gload16(gv + off, (char*)V_lds[cur ^ 1] + off);
      }
    }

    if (64 * kt <= qw + 31) {   // wave-uniform: this wave has unmasked rows
      const ushort* Kl = K_lds[cur];
      const ushort* Vl = V_lds[cur];

      // ---- S^T = K Q : 2 kv-subtiles x 8 d-slices ----
      f32x16 st[2] = {};
      __builtin_amdgcn_s_setprio(1);
      #pragma unroll
      for (int t = 0; t < 2; ++t) {
        const char* krow = (const char*)Kl + (32 * t + l31) * 256;
        const int klow = (32 * t + l31) & 15;
        #pragma unroll
        for (int s = 0; s < 8; ++s) {
          int chunk = (2 * s + hi) ^ klow;
          bf16x8 kf = *(const bf16x8*)(krow + chunk * 16);
          st[t] = __builtin_amdgcn_mfma_f32_32x32x16_bf16(kf, qf[s], st[t], 0, 0, 0);
        }
      }
      __builtin_amdgcn_s_setprio(0);

      // ---- causal mask (only near diagonal) ----
      if (64 * kt + 63 > qw) {
        #pragma unroll
        for (int t = 0; t < 2; ++t)
          #pragma unroll
          for (int r = 0; r < 16; ++r) {
            int kv = 64 * kt + 32 * t + (r & 3) + 8 * (r >> 2) + 4 * hi;
            if (kv > qrow) st[t][r] = -1e30f;
          }
      }

      // ---- online softmax, fully lane-local (q-row = l31) ----
      float t8[8];
      #pragma unroll
      for (int e = 0; e < 8; ++e)
        t8[e] = fmaxf(fmaxf(st[0][e], st[0][e + 8]), fmaxf(st[1][e], st[1][e + 8]));
      float t4a = fmaxf(fmaxf(t8[0], t8[1]), fmaxf(t8[2], t8[3]));
      float t4b = fmaxf(fmaxf(t8[4], t8[5]), fmaxf(t8[6], t8[7]));
      float mx = fmaxf(t4a, t4b);
      mx = fmaxf(mx, __shfl_xor(mx, 32));
      float mnew = fmaxf(mrow, mx);
      float alpha = exp2f(mrow - mnew);
      mrow = mnew;

      #pragma unroll
      for (int t = 0; t < 2; ++t)
        #pragma unroll
        for (int e = 0; e < 16; ++e) st[t][e] = exp2f(st[t][e] - mnew);
      f32x16 sv16 = st[0] + st[1];
      float s8[8];
      #pragma unroll
      for (int e = 0; e < 8; ++e) s8[e] = sv16[e] + sv16[e + 8];
      float rsum = ((s8[0] + s8[1]) + (s8[2] + s8[3])) + ((s8[4] + s8[5]) + (s8[6] + s8[7]));
      rsum += __shfl_xor(rsum, 32);
      lsum = lsum * alpha + rsum;

      #pragma unroll
      for (int dt = 0; dt < 4; ++dt) o[dt] *= alpha;

      // ---- pack P^T (B operand): cvt_pk + permlane32_swap (m214 recipe) ----
      bf16x8 pb[4];
      #pragma unroll
      for (int c = 0; c < 4; ++c) {
        const int ti = c >> 1, r0 = (c & 1) * 8;
        uint32_t a0 = cvtpk(st[ti][r0 + 0], st[ti][r0 + 1]);
        uint32_t b0 = cvtpk(st[ti][r0 + 4], st[ti][r0 + 5]);
        asm volatile("v_permlane32_swap_b32 %0, %1" : "+v"(a0), "+v"(b0));
        uint32_t a1 = cvtpk(st[ti][r0 + 2], st[ti][r0 + 3]);
        uint32_t b1 = cvtpk(st[ti][r0 + 6], st[ti][r0 + 7]);
        asm volatile("v_permlane32_swap_b32 %0, %1" : "+v"(a1), "+v"(b1));
        union { uint32_t u[4]; bf16x8 v; } pu;
        pu.u[0] = a0; pu.u[1] = a1; pu.u[2] = b0; pu.u[3] = b1;
        pb[c] = pu.v;
      }

      // ---- O^T += V^T P^T ----
      __builtin_amdgcn_s_setprio(1);
      #pragma unroll
      for (int dt = 0; dt < 4; ++dt) {
        const char* vrow = (const char*)Vl + (32 * dt + l31) * 128;
        const int dlow = (32 * dt + l31) & 7;
        #pragma unroll
        for (int c = 0; c < 4; ++c) {
          int chunk = (2 * c + hi) ^ dlow;
          bf16x8 vf = *(const bf16x8*)(vrow + chunk * 16);
          o[dt] = __builtin_amdgcn_mfma_f32_32x32x16_bf16(vf, pb[c], o[dt], 0, 0, 0);
        }
      }
      __builtin_amdgcn_s_setprio(0);
    }
    __syncthreads();
  }

  // ---- epilogue: divide by denom, store fp32 (4-contiguous d runs) ----
  const float inv = 1.0f / lsum;
  float* op = O + ((size_t)h * S_LEN + qrow) * D_DIM;
  #pragma unroll
  for (int dt = 0; dt < 4; ++dt)
    #pragma unroll
    for (int rq = 0; rq < 4; ++rq) {
      f32x4 vv;
      #pragma unroll
      for (int j = 0; j < 4; ++j) vv[j] = o[dt][rq * 4 + j] * inv;
      *(f32x4*)(op + 32 * dt + 8 * rq + 4 * hi) = vv;
    }
}

extern "C" void kernel_launch(void* const* d_in, const int* in_sizes, int n_in,
                              void* d_out, int out_size, void* d_ws, size_t ws_size,
                              hipStream_t stream) {
  const float* Q = (const float*)d_in[0];
  const float* K = (const float*)d_in[1];
  const float* V = (const float*)d_in[2];
  float* O = (float*)d_out;
  ushort* wsK = (ushort*)d_ws;
  ushort* wsV = wsK + (size_t)8 * NKT * TILE_USH;   // +4MB
  prep_k<<<1024, 256, 0, stream>>>(K, wsK);
  prep_v<<<1024, 256, 0, stream>>>(V, wsV);
  attn_fwd<<<512, 256, 0, stream>>>(Q, wsK, wsV, O);
}